// Round 1
// baseline (328.612 us; speedup 1.0000x reference)
//
#include <hip/hip_runtime.h>
#include <math.h>

#define NB 32
#define DIM 256
#define LHW 64
#define SCALE_QK 0.35355339059327373f

// ---------------------------------------------------------------------------
// K1: per-(b,c) plane row/col means.  x:(B,256,64,64) -> xh[b][c][h], xw[b][c][w]
// ---------------------------------------------------------------------------
__global__ __launch_bounds__(256) void k_reduce(const float* __restrict__ x,
                                                float* __restrict__ xh,
                                                float* __restrict__ xw) {
    __shared__ float s[64 * 68];          // pad 68 to break power-of-2 strides
    const int t = threadIdx.x;
    const float* p = x + (size_t)blockIdx.x * 4096;
#pragma unroll
    for (int i = 0; i < 4; ++i) {
        int idx4 = t + 256 * i;           // float4 index in plane (1024 total)
        float4 v = reinterpret_cast<const float4*>(p)[idx4];
        int h = idx4 >> 4;
        int w0 = (idx4 & 15) << 2;
        *reinterpret_cast<float4*>(&s[h * 68 + w0]) = v;
    }
    __syncthreads();
    if (t < 64) {                          // row sums -> xh (mean over w)
        float acc = 0.f;
#pragma unroll
        for (int j = 0; j < 16; ++j) {
            float4 v = *reinterpret_cast<const float4*>(&s[t * 68 + j * 4]);
            acc += v.x + v.y + v.z + v.w;
        }
        xh[(size_t)blockIdx.x * 64 + t] = acc * (1.0f / 64.0f);
    } else if (t < 128) {                  // col sums -> xw (mean over h)
        int w = t - 64;
        float acc = 0.f;
#pragma unroll
        for (int h = 0; h < 64; ++h) acc += s[h * 68 + w];
        xw[(size_t)blockIdx.x * 64 + w] = acc * (1.0f / 64.0f);
    }
}

// ---------------------------------------------------------------------------
// K2: per (b, axis, head): qkv = BN(w_qkv @ x_axis); q,k += pos; attention.
// grid = 128 blocks (b*4 + axis*2 + head), 256 threads.
// ---------------------------------------------------------------------------
__global__ __launch_bounds__(256) void k_qkv_attn(
    const float* __restrict__ xh, const float* __restrict__ xw,
    const float* __restrict__ w_qkv, const float* __restrict__ qscale,
    const float* __restrict__ qshift, const float* __restrict__ pos_h,
    const float* __restrict__ pos_w, float* __restrict__ outa) {
    const int blk = blockIdx.x;
    const int head = blk & 1;
    const int axis = (blk >> 1) & 1;
    const int b = blk >> 2;
    const float* xa = (axis ? xw : xh) + (size_t)b * DIM * 64;
    const float* pos = axis ? pos_w : pos_h;

    __shared__ float smem[16384];          // 64 KB, phase-unioned
    float* sx = smem;                      // phase 1: x_axis [c][l], 256*64
    float* sq = smem;                      // phase 2: qkv rows [24][64] (q0-7,k8-15,v16-23)
    float* sP = smem + 24 * 64;            // phase 2: logits [64][65]

    const int t = threadIdx.x;
    // stage x_axis (16384 floats)
#pragma unroll
    for (int i = 0; i < 16; ++i) {
        int idx4 = t + 256 * i;
        reinterpret_cast<float4*>(sx)[idx4] =
            reinterpret_cast<const float4*>(xa)[idx4];
    }
    __syncthreads();

    // qkv: each thread computes 6 of the 24 rows at its l
    const int l = t & 63, g = t >> 6;
    float acc[6] = {0.f, 0.f, 0.f, 0.f, 0.f, 0.f};
    int ocg[6];
#pragma unroll
    for (int i = 0; i < 6; ++i) {
        int r = g + 4 * i;                       // row 0..23
        ocg[i] = (r >> 3) * 16 + head * 8 + (r & 7);   // global qkv channel
    }
    for (int c = 0; c < 256; c += 4) {
        float x0 = sx[(c + 0) * 64 + l];
        float x1 = sx[(c + 1) * 64 + l];
        float x2 = sx[(c + 2) * 64 + l];
        float x3 = sx[(c + 3) * 64 + l];
#pragma unroll
        for (int i = 0; i < 6; ++i) {
            float4 wv = *reinterpret_cast<const float4*>(&w_qkv[ocg[i] * 256 + c]);
            acc[i] += wv.x * x0 + wv.y * x1 + wv.z * x2 + wv.w * x3;
        }
    }
    __syncthreads();                           // done reading sx; smem reused
    float vals[6];
#pragma unroll
    for (int i = 0; i < 6; ++i) {
        int r = g + 4 * i;
        float v = acc[i] * qscale[ocg[i]] + qshift[ocg[i]];
        if (r < 16) v += pos[(head * 8 + (r & 7)) * 64 + l];   // q and k get pos
        vals[i] = v;
    }
#pragma unroll
    for (int i = 0; i < 6; ++i) sq[(g + 4 * i) * 64 + l] = vals[i];
    __syncthreads();

    // logits S[i][j] = SCALE * sum_d q[d][i] k[d][j]
    {
        const int j = t & 63;
#pragma unroll
        for (int ii = 0; ii < 16; ++ii) {
            int i = g + 4 * ii;
            float s = 0.f;
#pragma unroll
            for (int d = 0; d < 8; ++d)
                s += sq[d * 64 + i] * sq[(8 + d) * 64 + j];
            sP[i * 65 + j] = s * SCALE_QK;
        }
    }
    __syncthreads();
    // softmax per row (thread-per-row, stride-65 conflict-free)
    if (t < 64) {
        float m = -1e30f;
        for (int j = 0; j < 64; ++j) m = fmaxf(m, sP[t * 65 + j]);
        float sum = 0.f;
        for (int j = 0; j < 64; ++j) {
            float e = __expf(sP[t * 65 + j] - m);
            sP[t * 65 + j] = e;
            sum += e;
        }
        float r = 1.0f / sum;
        for (int j = 0; j < 64; ++j) sP[t * 65 + j] *= r;
    }
    __syncthreads();
    // out[d][i] = sum_j P[i][j] v[d][j]
    {
        const int i = t & 63;
#pragma unroll
        for (int k2 = 0; k2 < 2; ++k2) {
            int d = g * 2 + k2;
            float acc2 = 0.f;
            for (int j = 0; j < 64; ++j)
                acc2 += sP[i * 65 + j] * sq[(16 + d) * 64 + j];
            outa[(((size_t)b * 2 + axis) * 16 + head * 8 + d) * 64 + i] = acc2;
        }
    }
}

// ---------------------------------------------------------------------------
// K3: fusion (16->256) with BN fold; also per-(b,axis,o) mean over l.
// axis 0: A = Ah*fs ; axis 1: A = Aw*fs + fb.  grid = 64 (b*2+axis).
// ---------------------------------------------------------------------------
__global__ __launch_bounds__(256) void k_fusion(
    const float* __restrict__ outa, const float* __restrict__ w_fusion,
    const float* __restrict__ fscale, const float* __restrict__ fshift,
    float* __restrict__ Ah, float* __restrict__ Aw, float* __restrict__ Amean) {
    const int blk = blockIdx.x;
    const int axis = blk & 1;
    const int b = blk >> 1;
    __shared__ float so[16 * 64];
    __shared__ float swf[256 * 16];
    const int t = threadIdx.x;
    reinterpret_cast<float4*>(so)[t] =
        reinterpret_cast<const float4*>(outa + (size_t)blk * 16 * 64)[t];
#pragma unroll
    for (int i = 0; i < 4; ++i) {
        int idx4 = t + 256 * i;               // row o = idx4/4, quad = idx4%4
        int o = idx4 >> 2, qd = idx4 & 3;
        reinterpret_cast<float4*>(swf)[idx4] =
            *reinterpret_cast<const float4*>(&w_fusion[o * 32 + axis * 16 + qd * 4]);
    }
    __syncthreads();
    const int l = t & 63, g = t >> 6;
    float xo[16];
#pragma unroll
    for (int cc = 0; cc < 16; ++cc) xo[cc] = so[cc * 64 + l];
    float* A = (axis ? Aw : Ah) + (size_t)b * DIM * 64;
    for (int i = 0; i < 64; ++i) {
        int o = g + 4 * i;
        float acc = 0.f;
#pragma unroll
        for (int q4 = 0; q4 < 4; ++q4) {
            float4 wv = *reinterpret_cast<const float4*>(&swf[o * 16 + q4 * 4]);
            acc += wv.x * xo[q4 * 4] + wv.y * xo[q4 * 4 + 1] +
                   wv.z * xo[q4 * 4 + 2] + wv.w * xo[q4 * 4 + 3];
        }
        float val = acc * fscale[o] + (axis ? fshift[o] : 0.0f);
        A[o * 64 + l] = val;
        float s = val;                         // wave reduce over l (64 lanes)
#pragma unroll
        for (int off = 32; off >= 1; off >>= 1) s += __shfl_xor(s, off, 64);
        if (l == 0) Amean[(size_t)blk * DIM + o] = s * (1.0f / 64.0f);
    }
}

// ---------------------------------------------------------------------------
// K4: SE gate per batch: g -> silu MLP -> 0.1*sigmoid.  grid = 32.
// ---------------------------------------------------------------------------
__global__ __launch_bounds__(256) void k_gate(
    const float* __restrict__ Amean, const float* __restrict__ w_g1,
    const float* __restrict__ g1s, const float* __restrict__ g1b,
    const float* __restrict__ w_g2, const float* __restrict__ g2s,
    const float* __restrict__ g2b, float* __restrict__ g2out) {
    const int b = blockIdx.x;
    __shared__ float sg[256];
    __shared__ float sg1[64];
    const int t = threadIdx.x;
    sg[t] = Amean[(size_t)(b * 2) * 256 + t] + Amean[(size_t)(b * 2 + 1) * 256 + t];
    __syncthreads();
    if (t < 64) {
        float acc = 0.f;
        for (int c = 0; c < 256; c += 4) {
            float4 wv = *reinterpret_cast<const float4*>(&w_g1[t * 256 + c]);
            acc += wv.x * sg[c] + wv.y * sg[c + 1] + wv.z * sg[c + 2] + wv.w * sg[c + 3];
        }
        float v = acc * g1s[t] + g1b[t];
        sg1[t] = v / (1.0f + __expf(-v));            // silu
    }
    __syncthreads();
    {
        float acc = 0.f;
        for (int j = 0; j < 64; j += 4) {
            float4 wv = *reinterpret_cast<const float4*>(&w_g2[t * 64 + j]);
            acc += wv.x * sg1[j] + wv.y * sg1[j + 1] + wv.z * sg1[j + 2] + wv.w * sg1[j + 3];
        }
        float v = acc * g2s[t] + g2b[t];
        g2out[(size_t)b * 256 + t] = 0.1f / (1.0f + __expf(-v));   // 0.1*sigmoid folded
    }
}

// ---------------------------------------------------------------------------
// K5: out = x + g2[b,o]*(Ah[b,o,h] + Aw[b,o,w]).  grid = 8192 (b*256+o).
// ---------------------------------------------------------------------------
__global__ __launch_bounds__(256) void k_final(
    const float* __restrict__ x, const float* __restrict__ Ah,
    const float* __restrict__ Aw, const float* __restrict__ g2,
    float* __restrict__ out) {
    const int bo = blockIdx.x;
    __shared__ float sAh[64], sAw[64];
    const int t = threadIdx.x;
    if (t < 64) sAh[t] = Ah[(size_t)bo * 64 + t];
    else if (t < 128) sAw[t - 64] = Aw[(size_t)bo * 64 + (t - 64)];
    const float gv = g2[bo];
    __syncthreads();
    const float* px = x + (size_t)bo * 4096;
    float* po = out + (size_t)bo * 4096;
#pragma unroll
    for (int i = 0; i < 4; ++i) {
        int idx4 = t + 256 * i;
        float4 xv = reinterpret_cast<const float4*>(px)[idx4];
        int h = idx4 >> 4, w0 = (idx4 & 15) << 2;
        float a = sAh[h];
        float4 r;
        r.x = xv.x + gv * (a + sAw[w0 + 0]);
        r.y = xv.y + gv * (a + sAw[w0 + 1]);
        r.z = xv.z + gv * (a + sAw[w0 + 2]);
        r.w = xv.w + gv * (a + sAw[w0 + 3]);
        reinterpret_cast<float4*>(po)[idx4] = r;
    }
}

extern "C" void kernel_launch(void* const* d_in, const int* in_sizes, int n_in,
                              void* d_out, int out_size, void* d_ws, size_t ws_size,
                              hipStream_t stream) {
    const float* x      = (const float*)d_in[0];
    const float* w_qkv  = (const float*)d_in[1];
    const float* qscale = (const float*)d_in[2];
    const float* qshift = (const float*)d_in[3];
    const float* pos_h  = (const float*)d_in[4];
    const float* pos_w  = (const float*)d_in[5];
    const float* w_fus  = (const float*)d_in[6];
    const float* fscale = (const float*)d_in[7];
    const float* fshift = (const float*)d_in[8];
    const float* w_g1   = (const float*)d_in[9];
    const float* g1s    = (const float*)d_in[10];
    const float* g1b    = (const float*)d_in[11];
    const float* w_g2   = (const float*)d_in[12];
    const float* g2s    = (const float*)d_in[13];
    const float* g2b    = (const float*)d_in[14];
    float* out = (float*)d_out;

    // workspace layout (floats), total ~8.75 MB
    float* ws    = (float*)d_ws;
    float* xh    = ws;                    // 32*256*64 = 524288
    float* xw    = xh + 524288;           // 524288
    float* outa  = xw + 524288;           // 32*2*16*64 = 65536
    float* Ah    = outa + 65536;          // 524288
    float* Aw    = Ah + 524288;           // 524288
    float* Amean = Aw + 524288;           // 32*2*256 = 16384
    float* g2w   = Amean + 16384;         // 32*256 = 8192

    k_reduce<<<NB * DIM, 256, 0, stream>>>(x, xh, xw);
    k_qkv_attn<<<NB * 4, 256, 0, stream>>>(xh, xw, w_qkv, qscale, qshift,
                                           pos_h, pos_w, outa);
    k_fusion<<<NB * 2, 256, 0, stream>>>(outa, w_fus, fscale, fshift, Ah, Aw, Amean);
    k_gate<<<NB, 256, 0, stream>>>(Amean, w_g1, g1s, g1b, w_g2, g2s, g2b, g2w);
    k_final<<<NB * DIM, 256, 0, stream>>>(x, Ah, Aw, g2w, out);
}

// Round 3
// 307.831 us; speedup vs baseline: 1.0675x; 1.0675x over previous
//
#include <hip/hip_runtime.h>
#include <math.h>

#define NB 32
#define DIM 256
#define SCALE_QK 0.35355339059327373f

typedef float floatx4 __attribute__((ext_vector_type(4)));   // native vec for nontemporal

// ---------------------------------------------------------------------------
// K1: per-(b,c) plane row/col means.  x:(B,256,64,64) -> xh[b][c][h], xw[b][c][w]
// ---------------------------------------------------------------------------
__global__ __launch_bounds__(256) void k_reduce(const float* __restrict__ x,
                                                float* __restrict__ xh,
                                                float* __restrict__ xw) {
    __shared__ float s[64 * 68];          // pad 68 to break power-of-2 strides
    const int t = threadIdx.x;
    const float* p = x + (size_t)blockIdx.x * 4096;
#pragma unroll
    for (int i = 0; i < 4; ++i) {
        int idx4 = t + 256 * i;           // float4 index in plane (1024 total)
        float4 v = reinterpret_cast<const float4*>(p)[idx4];
        int h = idx4 >> 4;
        int w0 = (idx4 & 15) << 2;
        *reinterpret_cast<float4*>(&s[h * 68 + w0]) = v;
    }
    __syncthreads();
    if (t < 64) {                          // row sums -> xh (mean over w)
        float acc = 0.f;
#pragma unroll
        for (int j = 0; j < 16; ++j) {
            float4 v = *reinterpret_cast<const float4*>(&s[t * 68 + j * 4]);
            acc += v.x + v.y + v.z + v.w;
        }
        xh[(size_t)blockIdx.x * 64 + t] = acc * (1.0f / 64.0f);
    } else if (t < 128) {                  // col sums -> xw (mean over h)
        int w = t - 64;
        float acc = 0.f;
#pragma unroll
        for (int h = 0; h < 64; ++h) acc += s[h * 68 + w];
        xw[(size_t)blockIdx.x * 64 + w] = acc * (1.0f / 64.0f);
    }
}

// ---------------------------------------------------------------------------
// K2: per (b, axis, head): qkv = BN(w_qkv @ x_axis); q,k += pos; attention.
// Emits outa[(b,axis,c),l] and its mean over l (outam).
// grid = 128 blocks (b*4 + axis*2 + head), 256 threads.
// ---------------------------------------------------------------------------
__global__ __launch_bounds__(256) void k_qkv_attn(
    const float* __restrict__ xh, const float* __restrict__ xw,
    const float* __restrict__ w_qkv, const float* __restrict__ qscale,
    const float* __restrict__ qshift, const float* __restrict__ pos_h,
    const float* __restrict__ pos_w, float* __restrict__ outa,
    float* __restrict__ outam) {
    const int blk = blockIdx.x;
    const int head = blk & 1;
    const int axis = (blk >> 1) & 1;
    const int b = blk >> 2;
    const float* xa = (axis ? xw : xh) + (size_t)b * DIM * 64;
    const float* pos = axis ? pos_w : pos_h;

    __shared__ float smem[16384];          // 64 KB, phase-unioned
    float* sx = smem;                      // phase 1: x_axis [c][l], 256*64
    float* sq = smem;                      // phase 2: qkv rows [24][64] (q0-7,k8-15,v16-23)
    float* sP = smem + 24 * 64;            // phase 2: logits [64][65]

    const int t = threadIdx.x;
#pragma unroll
    for (int i = 0; i < 16; ++i) {
        int idx4 = t + 256 * i;
        reinterpret_cast<float4*>(sx)[idx4] =
            reinterpret_cast<const float4*>(xa)[idx4];
    }
    __syncthreads();

    const int l = t & 63, g = t >> 6;
    float acc[6] = {0.f, 0.f, 0.f, 0.f, 0.f, 0.f};
    int ocg[6];
#pragma unroll
    for (int i = 0; i < 6; ++i) {
        int r = g + 4 * i;                       // row 0..23
        ocg[i] = (r >> 3) * 16 + head * 8 + (r & 7);   // global qkv channel
    }
    for (int c = 0; c < 256; c += 4) {
        float x0 = sx[(c + 0) * 64 + l];
        float x1 = sx[(c + 1) * 64 + l];
        float x2 = sx[(c + 2) * 64 + l];
        float x3 = sx[(c + 3) * 64 + l];
#pragma unroll
        for (int i = 0; i < 6; ++i) {
            float4 wv = *reinterpret_cast<const float4*>(&w_qkv[ocg[i] * 256 + c]);
            acc[i] += wv.x * x0 + wv.y * x1 + wv.z * x2 + wv.w * x3;
        }
    }
    __syncthreads();                           // done reading sx; smem reused
    float vals[6];
#pragma unroll
    for (int i = 0; i < 6; ++i) {
        int r = g + 4 * i;
        float v = acc[i] * qscale[ocg[i]] + qshift[ocg[i]];
        if (r < 16) v += pos[(head * 8 + (r & 7)) * 64 + l];   // q and k get pos
        vals[i] = v;
    }
#pragma unroll
    for (int i = 0; i < 6; ++i) sq[(g + 4 * i) * 64 + l] = vals[i];
    __syncthreads();

    // logits S[i][j] = SCALE * sum_d q[d][i] k[d][j]
    {
        const int j = t & 63;
#pragma unroll
        for (int ii = 0; ii < 16; ++ii) {
            int i = g + 4 * ii;
            float s = 0.f;
#pragma unroll
            for (int d = 0; d < 8; ++d)
                s += sq[d * 64 + i] * sq[(8 + d) * 64 + j];
            sP[i * 65 + j] = s * SCALE_QK;
        }
    }
    __syncthreads();
    if (t < 64) {                              // softmax per row, stride-65
        float m = -1e30f;
        for (int j = 0; j < 64; ++j) m = fmaxf(m, sP[t * 65 + j]);
        float sum = 0.f;
        for (int j = 0; j < 64; ++j) {
            float e = __expf(sP[t * 65 + j] - m);
            sP[t * 65 + j] = e;
            sum += e;
        }
        float r = 1.0f / sum;
        for (int j = 0; j < 64; ++j) sP[t * 65 + j] *= r;
    }
    __syncthreads();
    // out[d][i] = sum_j P[i][j] v[d][j]; also emit mean over i
    {
        const int i = t & 63;
#pragma unroll
        for (int k2 = 0; k2 < 2; ++k2) {
            int d = g * 2 + k2;
            float acc2 = 0.f;
            for (int j = 0; j < 64; ++j)
                acc2 += sP[i * 65 + j] * sq[(16 + d) * 64 + j];
            outa[(((size_t)b * 2 + axis) * 16 + head * 8 + d) * 64 + i] = acc2;
            float s = acc2;                     // wave butterfly over the 64 lanes
#pragma unroll
            for (int off = 32; off >= 1; off >>= 1) s += __shfl_xor(s, off, 64);
            if (i == 0)
                outam[((size_t)b * 2 + axis) * 16 + head * 8 + d] = s * (1.0f / 64.0f);
        }
    }
}

// ---------------------------------------------------------------------------
// K3: SE gate per batch.  Amean[o] = fscale*(w_fusion[o,:] . outam[b,:]) + fshift,
// then silu MLP -> 0.1*sigmoid.  grid = 32.
// ---------------------------------------------------------------------------
__global__ __launch_bounds__(256) void k_gate(
    const float* __restrict__ outam, const float* __restrict__ w_fusion,
    const float* __restrict__ fscale, const float* __restrict__ fshift,
    const float* __restrict__ w_g1, const float* __restrict__ g1s,
    const float* __restrict__ g1b, const float* __restrict__ w_g2,
    const float* __restrict__ g2s, const float* __restrict__ g2b,
    float* __restrict__ g2out) {
    const int b = blockIdx.x;
    __shared__ float sm[32];
    __shared__ float sg[256];
    __shared__ float sg1[64];
    const int t = threadIdx.x;
    if (t < 32) sm[t] = outam[(size_t)b * 32 + t];
    __syncthreads();
    {
        float acc = 0.f;
#pragma unroll
        for (int c = 0; c < 32; c += 4) {
            float4 wv = *reinterpret_cast<const float4*>(&w_fusion[t * 32 + c]);
            acc += wv.x * sm[c] + wv.y * sm[c + 1] + wv.z * sm[c + 2] + wv.w * sm[c + 3];
        }
        sg[t] = acc * fscale[t] + fshift[t];
    }
    __syncthreads();
    if (t < 64) {
        float acc = 0.f;
        for (int c = 0; c < 256; c += 4) {
            float4 wv = *reinterpret_cast<const float4*>(&w_g1[t * 256 + c]);
            acc += wv.x * sg[c] + wv.y * sg[c + 1] + wv.z * sg[c + 2] + wv.w * sg[c + 3];
        }
        float v = acc * g1s[t] + g1b[t];
        sg1[t] = v / (1.0f + __expf(-v));            // silu
    }
    __syncthreads();
    {
        float acc = 0.f;
#pragma unroll
        for (int j = 0; j < 64; j += 4) {
            float4 wv = *reinterpret_cast<const float4*>(&w_g2[t * 64 + j]);
            acc += wv.x * sg1[j] + wv.y * sg1[j + 1] + wv.z * sg1[j + 2] + wv.w * sg1[j + 3];
        }
        float v = acc * g2s[t] + g2b[t];
        g2out[(size_t)b * 256 + t] = 0.1f / (1.0f + __expf(-v));   // 0.1*sigmoid folded
    }
}

// ---------------------------------------------------------------------------
// K4: fusion row recompute + epilogue.
// out = x + gv*(fscale*(rowh[h]+roww[w]) + fshift).  grid = 8192 (b*256+o).
// ---------------------------------------------------------------------------
__global__ __launch_bounds__(256) void k_final(
    const float* __restrict__ x, const float* __restrict__ outa,
    const float* __restrict__ w_fusion, const float* __restrict__ fscale,
    const float* __restrict__ fshift, const float* __restrict__ g2,
    float* __restrict__ out) {
    const int bo = blockIdx.x;
    const int b = bo >> 8, o = bo & 255;
    __shared__ float so[2048];             // outa[b] : [axis][c][l]
    __shared__ float sP[64], sQ[64];
    const int t = threadIdx.x;
    const float* oa = outa + (size_t)b * 2048;
    reinterpret_cast<float4*>(so)[t] = reinterpret_cast<const float4*>(oa)[t];
    reinterpret_cast<float4*>(so)[t + 256] = reinterpret_cast<const float4*>(oa)[t + 256];
    const float gv = g2[bo];               // already 0.1*sigmoid
    __syncthreads();
    if (t < 64) {                          // rowh over axis 0 (block-uniform weights)
        float acc = 0.f;
#pragma unroll
        for (int c = 0; c < 16; ++c) acc += w_fusion[o * 32 + c] * so[c * 64 + t];
        sP[t] = gv * (fscale[o] * acc + fshift[o]);
    } else if (t < 128) {                  // roww over axis 1
        int w = t - 64;
        float acc = 0.f;
#pragma unroll
        for (int c = 0; c < 16; ++c)
            acc += w_fusion[o * 32 + 16 + c] * so[1024 + c * 64 + w];
        sQ[w] = gv * fscale[o] * acc;
    }
    __syncthreads();
    const float* px = x + (size_t)bo * 4096;
    float* po = out + (size_t)bo * 4096;
#pragma unroll
    for (int i = 0; i < 4; ++i) {
        int idx4 = t + 256 * i;
        float4 xv = reinterpret_cast<const float4*>(px)[idx4];
        int h = idx4 >> 4, w0 = (idx4 & 15) << 2;
        float a = sP[h];
        floatx4 r;
        r.x = xv.x + a + sQ[w0 + 0];
        r.y = xv.y + a + sQ[w0 + 1];
        r.z = xv.z + a + sQ[w0 + 2];
        r.w = xv.w + a + sQ[w0 + 3];
        __builtin_nontemporal_store(r, reinterpret_cast<floatx4*>(po) + idx4);
    }
}

extern "C" void kernel_launch(void* const* d_in, const int* in_sizes, int n_in,
                              void* d_out, int out_size, void* d_ws, size_t ws_size,
                              hipStream_t stream) {
    const float* x      = (const float*)d_in[0];
    const float* w_qkv  = (const float*)d_in[1];
    const float* qscale = (const float*)d_in[2];
    const float* qshift = (const float*)d_in[3];
    const float* pos_h  = (const float*)d_in[4];
    const float* pos_w  = (const float*)d_in[5];
    const float* w_fus  = (const float*)d_in[6];
    const float* fscale = (const float*)d_in[7];
    const float* fshift = (const float*)d_in[8];
    const float* w_g1   = (const float*)d_in[9];
    const float* g1s    = (const float*)d_in[10];
    const float* g1b    = (const float*)d_in[11];
    const float* w_g2   = (const float*)d_in[12];
    const float* g2s    = (const float*)d_in[13];
    const float* g2b    = (const float*)d_in[14];
    float* out = (float*)d_out;

    // workspace layout (floats)
    float* ws    = (float*)d_ws;
    float* xh    = ws;                    // 32*256*64 = 524288
    float* xw    = xh + 524288;           // 524288
    float* outa  = xw + 524288;           // 32*2*16*64 = 65536
    float* outam = outa + 65536;          // 32*32 = 1024
    float* g2w   = outam + 1024;          // 32*256 = 8192

    k_reduce<<<NB * DIM, 256, 0, stream>>>(x, xh, xw);
    k_qkv_attn<<<NB * 4, 256, 0, stream>>>(xh, xw, w_qkv, qscale, qshift,
                                           pos_h, pos_w, outa, outam);
    k_gate<<<NB, 256, 0, stream>>>(outam, w_fus, fscale, fshift,
                                   w_g1, g1s, g1b, w_g2, g2s, g2b, g2w);
    k_final<<<NB * DIM, 256, 0, stream>>>(x, outa, w_fus, fscale, fshift, g2w, out);
}

// Round 4
// 305.326 us; speedup vs baseline: 1.0763x; 1.0082x over previous
//
#include <hip/hip_runtime.h>
#include <math.h>

#define NB 32
#define DIM 256
#define SCALE_QK 0.35355339059327373f

typedef float floatx4 __attribute__((ext_vector_type(4)));   // native vec for nontemporal

// ---------------------------------------------------------------------------
// K1: per-(b,c) plane row/col means.  x:(B,256,64,64) -> xh[b][c][h], xw[b][c][w]
// Also zeroes the 32 per-batch arrival counters used by K2's fused gate.
// ---------------------------------------------------------------------------
__global__ __launch_bounds__(256) void k_reduce(const float* __restrict__ x,
                                                float* __restrict__ xh,
                                                float* __restrict__ xw,
                                                int* __restrict__ cnt) {
    __shared__ float s[64 * 68];          // pad 68 to break power-of-2 strides
    const int t = threadIdx.x;
    if (blockIdx.x == 0 && t < 32) cnt[t] = 0;   // stream-ordered before K2
    const float* p = x + (size_t)blockIdx.x * 4096;
#pragma unroll
    for (int i = 0; i < 4; ++i) {
        int idx4 = t + 256 * i;           // float4 index in plane (1024 total)
        float4 v = reinterpret_cast<const float4*>(p)[idx4];
        int h = idx4 >> 4;
        int w0 = (idx4 & 15) << 2;
        *reinterpret_cast<float4*>(&s[h * 68 + w0]) = v;
    }
    __syncthreads();
    if (t < 64) {                          // row sums -> xh (mean over w)
        float acc = 0.f;
#pragma unroll
        for (int j = 0; j < 16; ++j) {
            float4 v = *reinterpret_cast<const float4*>(&s[t * 68 + j * 4]);
            acc += v.x + v.y + v.z + v.w;
        }
        xh[(size_t)blockIdx.x * 64 + t] = acc * (1.0f / 64.0f);
    } else if (t < 128) {                  // col sums -> xw (mean over h)
        int w = t - 64;
        float acc = 0.f;
#pragma unroll
        for (int h = 0; h < 64; ++h) acc += s[h * 68 + w];
        xw[(size_t)blockIdx.x * 64 + w] = acc * (1.0f / 64.0f);
    }
}

// ---------------------------------------------------------------------------
// K2: per (b, axis, head): qkv = BN(w_qkv @ x_axis); q,k += pos; attention.
// Emits outa[(b,axis,c),l] + outam mean slice; the LAST block of each batch
// (device-scope atomic arrival) runs the SE gate MLP inline -> g2out.
// grid = 128 blocks (b*4 + axis*2 + head), 256 threads.
// ---------------------------------------------------------------------------
__global__ __launch_bounds__(256) void k_qkv_attn(
    const float* __restrict__ xh, const float* __restrict__ xw,
    const float* __restrict__ w_qkv, const float* __restrict__ qscale,
    const float* __restrict__ qshift, const float* __restrict__ pos_h,
    const float* __restrict__ pos_w, float* __restrict__ outa,
    float* __restrict__ outam, int* __restrict__ cnt,
    const float* __restrict__ w_fusion, const float* __restrict__ fscale,
    const float* __restrict__ fshift, const float* __restrict__ w_g1,
    const float* __restrict__ g1s, const float* __restrict__ g1b,
    const float* __restrict__ w_g2, const float* __restrict__ g2s,
    const float* __restrict__ g2b, float* __restrict__ g2out) {
    const int blk = blockIdx.x;
    const int head = blk & 1;
    const int axis = (blk >> 1) & 1;
    const int b = blk >> 2;
    const float* xa = (axis ? xw : xh) + (size_t)b * DIM * 64;
    const float* pos = axis ? pos_w : pos_h;

    __shared__ float smem[16384];          // 64 KB, phase-unioned
    __shared__ int sIsLast;
    float* sx = smem;                      // phase 1: x_axis [c][l], 256*64
    float* sq = smem;                      // phase 2: qkv rows [24][64] (q0-7,k8-15,v16-23)
    float* sP = smem + 24 * 64;            // phase 2: logits [64][65]

    const int t = threadIdx.x;
#pragma unroll
    for (int i = 0; i < 16; ++i) {
        int idx4 = t + 256 * i;
        reinterpret_cast<float4*>(sx)[idx4] =
            reinterpret_cast<const float4*>(xa)[idx4];
    }
    __syncthreads();

    const int l = t & 63, g = t >> 6;
    float acc[6] = {0.f, 0.f, 0.f, 0.f, 0.f, 0.f};
    int ocg[6];
#pragma unroll
    for (int i = 0; i < 6; ++i) {
        int r = g + 4 * i;                       // row 0..23
        ocg[i] = (r >> 3) * 16 + head * 8 + (r & 7);   // global qkv channel
    }
    for (int c = 0; c < 256; c += 4) {
        float x0 = sx[(c + 0) * 64 + l];
        float x1 = sx[(c + 1) * 64 + l];
        float x2 = sx[(c + 2) * 64 + l];
        float x3 = sx[(c + 3) * 64 + l];
#pragma unroll
        for (int i = 0; i < 6; ++i) {
            float4 wv = *reinterpret_cast<const float4*>(&w_qkv[ocg[i] * 256 + c]);
            acc[i] += wv.x * x0 + wv.y * x1 + wv.z * x2 + wv.w * x3;
        }
    }
    __syncthreads();                           // done reading sx; smem reused
    float vals[6];
#pragma unroll
    for (int i = 0; i < 6; ++i) {
        int r = g + 4 * i;
        float v = acc[i] * qscale[ocg[i]] + qshift[ocg[i]];
        if (r < 16) v += pos[(head * 8 + (r & 7)) * 64 + l];   // q and k get pos
        vals[i] = v;
    }
#pragma unroll
    for (int i = 0; i < 6; ++i) sq[(g + 4 * i) * 64 + l] = vals[i];
    __syncthreads();

    // logits S[i][j] = SCALE * sum_d q[d][i] k[d][j]
    {
        const int j = t & 63;
#pragma unroll
        for (int ii = 0; ii < 16; ++ii) {
            int i = g + 4 * ii;
            float s = 0.f;
#pragma unroll
            for (int d = 0; d < 8; ++d)
                s += sq[d * 64 + i] * sq[(8 + d) * 64 + j];
            sP[i * 65 + j] = s * SCALE_QK;
        }
    }
    __syncthreads();
    if (t < 64) {                              // softmax per row, stride-65
        float m = -1e30f;
        for (int j = 0; j < 64; ++j) m = fmaxf(m, sP[t * 65 + j]);
        float sum = 0.f;
        for (int j = 0; j < 64; ++j) {
            float e = __expf(sP[t * 65 + j] - m);
            sP[t * 65 + j] = e;
            sum += e;
        }
        float r = 1.0f / sum;
        for (int j = 0; j < 64; ++j) sP[t * 65 + j] *= r;
    }
    __syncthreads();
    // out[d][i] = sum_j P[i][j] v[d][j]; also emit mean over i
    {
        const int i = t & 63;
#pragma unroll
        for (int k2 = 0; k2 < 2; ++k2) {
            int d = g * 2 + k2;
            float acc2 = 0.f;
            for (int j = 0; j < 64; ++j)
                acc2 += sP[i * 65 + j] * sq[(16 + d) * 64 + j];
            outa[(((size_t)b * 2 + axis) * 16 + head * 8 + d) * 64 + i] = acc2;
            float s = acc2;                     // wave butterfly over the 64 lanes
#pragma unroll
            for (int off = 32; off >= 1; off >>= 1) s += __shfl_xor(s, off, 64);
            if (i == 0)
                outam[((size_t)b * 2 + axis) * 16 + head * 8 + d] = s * (1.0f / 64.0f);
        }
    }

    // ---- last block of this batch runs the SE gate inline -------------------
    __threadfence();                           // release outam writes (device scope)
    if (t == 0) sIsLast = (atomicAdd(&cnt[b], 1) == 3) ? 1 : 0;
    __syncthreads();
    if (sIsLast) {
        float* sm  = smem;                     // 32
        float* sg  = smem + 64;                // 256
        float* sg1 = smem + 64 + 256;          // 64
        if (t < 32)
            sm[t] = __hip_atomic_load(&outam[(size_t)b * 32 + t],
                                      __ATOMIC_ACQUIRE, __HIP_MEMORY_SCOPE_AGENT);
        __syncthreads();
        {
            float a2 = 0.f;
#pragma unroll
            for (int c = 0; c < 32; c += 4) {
                float4 wv = *reinterpret_cast<const float4*>(&w_fusion[t * 32 + c]);
                a2 += wv.x * sm[c] + wv.y * sm[c + 1] + wv.z * sm[c + 2] + wv.w * sm[c + 3];
            }
            sg[t] = a2 * fscale[t] + fshift[t];
        }
        __syncthreads();
        if (t < 64) {
            float a2 = 0.f;
            for (int c = 0; c < 256; c += 4) {
                float4 wv = *reinterpret_cast<const float4*>(&w_g1[t * 256 + c]);
                a2 += wv.x * sg[c] + wv.y * sg[c + 1] + wv.z * sg[c + 2] + wv.w * sg[c + 3];
            }
            float v = a2 * g1s[t] + g1b[t];
            sg1[t] = v / (1.0f + __expf(-v));            // silu
        }
        __syncthreads();
        {
            float a2 = 0.f;
#pragma unroll
            for (int j = 0; j < 64; j += 4) {
                float4 wv = *reinterpret_cast<const float4*>(&w_g2[t * 64 + j]);
                a2 += wv.x * sg1[j] + wv.y * sg1[j + 1] + wv.z * sg1[j + 2] + wv.w * sg1[j + 3];
            }
            float v = a2 * g2s[t] + g2b[t];
            g2out[(size_t)b * 256 + t] = 0.1f / (1.0f + __expf(-v));   // 0.1*sigmoid folded
        }
    }
}

// ---------------------------------------------------------------------------
// K3: fusion row recompute + epilogue.
// out = x + gv*(fscale*(rowh[h]+roww[w]) + fshift).  grid = 8192 (b*256+o).
// ---------------------------------------------------------------------------
__global__ __launch_bounds__(256) void k_final(
    const float* __restrict__ x, const float* __restrict__ outa,
    const float* __restrict__ w_fusion, const float* __restrict__ fscale,
    const float* __restrict__ fshift, const float* __restrict__ g2,
    float* __restrict__ out) {
    const int bo = blockIdx.x;
    const int b = bo >> 8, o = bo & 255;
    __shared__ float so[2048];             // outa[b] : [axis][c][l]
    __shared__ float sP[64], sQ[64];
    const int t = threadIdx.x;
    const float* oa = outa + (size_t)b * 2048;
    reinterpret_cast<float4*>(so)[t] = reinterpret_cast<const float4*>(oa)[t];
    reinterpret_cast<float4*>(so)[t + 256] = reinterpret_cast<const float4*>(oa)[t + 256];
    const float gv = g2[bo];               // already 0.1*sigmoid
    __syncthreads();
    if (t < 64) {                          // rowh over axis 0 (block-uniform weights)
        float acc = 0.f;
#pragma unroll
        for (int c = 0; c < 16; ++c) acc += w_fusion[o * 32 + c] * so[c * 64 + t];
        sP[t] = gv * (fscale[o] * acc + fshift[o]);
    } else if (t < 128) {                  // roww over axis 1
        int w = t - 64;
        float acc = 0.f;
#pragma unroll
        for (int c = 0; c < 16; ++c)
            acc += w_fusion[o * 32 + 16 + c] * so[1024 + c * 64 + w];
        sQ[w] = gv * fscale[o] * acc;
    }
    __syncthreads();
    const float* px = x + (size_t)bo * 4096;
    float* po = out + (size_t)bo * 4096;
#pragma unroll
    for (int i = 0; i < 4; ++i) {
        int idx4 = t + 256 * i;
        float4 xv = reinterpret_cast<const float4*>(px)[idx4];
        int h = idx4 >> 4, w0 = (idx4 & 15) << 2;
        float a = sP[h];
        floatx4 r;
        r.x = xv.x + a + sQ[w0 + 0];
        r.y = xv.y + a + sQ[w0 + 1];
        r.z = xv.z + a + sQ[w0 + 2];
        r.w = xv.w + a + sQ[w0 + 3];
        __builtin_nontemporal_store(r, reinterpret_cast<floatx4*>(po) + idx4);
    }
}

extern "C" void kernel_launch(void* const* d_in, const int* in_sizes, int n_in,
                              void* d_out, int out_size, void* d_ws, size_t ws_size,
                              hipStream_t stream) {
    const float* x      = (const float*)d_in[0];
    const float* w_qkv  = (const float*)d_in[1];
    const float* qscale = (const float*)d_in[2];
    const float* qshift = (const float*)d_in[3];
    const float* pos_h  = (const float*)d_in[4];
    const float* pos_w  = (const float*)d_in[5];
    const float* w_fus  = (const float*)d_in[6];
    const float* fscale = (const float*)d_in[7];
    const float* fshift = (const float*)d_in[8];
    const float* w_g1   = (const float*)d_in[9];
    const float* g1s    = (const float*)d_in[10];
    const float* g1b    = (const float*)d_in[11];
    const float* w_g2   = (const float*)d_in[12];
    const float* g2s    = (const float*)d_in[13];
    const float* g2b    = (const float*)d_in[14];
    float* out = (float*)d_out;

    // workspace layout (floats)
    float* ws    = (float*)d_ws;
    float* xh    = ws;                    // 32*256*64 = 524288
    float* xw    = xh + 524288;           // 524288
    float* outa  = xw + 524288;           // 32*2*16*64 = 65536
    float* outam = outa + 65536;          // 32*32 = 1024
    float* g2w   = outam + 1024;          // 32*256 = 8192
    int*   cnt   = (int*)(g2w + 8192);    // 32 arrival counters

    k_reduce<<<NB * DIM, 256, 0, stream>>>(x, xh, xw, cnt);
    k_qkv_attn<<<NB * 4, 256, 0, stream>>>(xh, xw, w_qkv, qscale, qshift,
                                           pos_h, pos_w, outa, outam, cnt,
                                           w_fus, fscale, fshift,
                                           w_g1, g1s, g1b, w_g2, g2s, g2b, g2w);
    k_final<<<NB * DIM, 256, 0, stream>>>(x, outa, w_fus, fscale, fshift, g2w, out);
}